// Round 2
// baseline (246.555 us; speedup 1.0000x reference)
//
#include <hip/hip_runtime.h>

// Problem constants (from reference setup_inputs):
//   x: (1, 3, 128, 128) fp32
//   w: (3, 124, 124, 25, 5, 5) fp32
//   q: (3, 124, 124, 25, 5, 5) fp32
//   out: (1, 3, 124, 124, 25) fp32
// out[o] = log( prod_{k=0..24} (1.1 + atan(10*(x_k*w_k - q_k))/pi) )
//
// R5 design: persistent blocks + double-buffered LDS + counted vmcnt pipeline.
// R3/R4 post-mortem: two opposite memory designs (register scatter @63% occ,
// contiguous global_load_lds @26% occ) both landed at 87 us with idle pipes
// (VALU 14%, HBM 22%, conflicts 0). The invariant was the phase structure:
// issue -> vmcnt(0) DRAIN -> compute -> block dies. Memory queue empties at
// every block boundary; effective stream 2.65 TB/s vs 6.3 achievable.
// Here: grid=256 persistent (1 block/CU, LDS 100 KB), each block walks tiles
// stride-256. Per tile each wave issues EXACTLY 14 DMA (6x16B + 1x4B per
// array, uniform so the count is exact), then waits vmcnt(14) -- i.e. waits
// only for tile t while tile t+1's 51.2 KB stays in flight ACROSS the raw
// s_barrier (NOT __syncthreads, which drains vmcnt(0)). Loads are in flight
// continuously; no launch gaps, no drains in the steady loop.

#define IMG    128
#define OUT    124
#define NUM    25
#define NOUT   (3 * OUT * OUT * NUM)        // 1,153,200 outputs
#define OPB    256                          // threads per block = outputs per tile
#define NTILES ((NOUT + OPB - 1) / OPB)     // 4505
#define PBLK   256                          // persistent blocks: 1 per CU
#define TILEF  (OPB * NUM)                  // 6400 floats per array per tile
#define WQF    (NOUT * NUM)                 // 28,830,000 floats in w (and in q)

// Minimax atan, |err| ~ 2e-6 over all inputs. Range-reduce with v_rcp_f32.
__device__ __forceinline__ float fast_atan(float z) {
    float az  = __builtin_fabsf(z);
    float r   = __builtin_amdgcn_rcpf(az);
    bool  big = az > 1.0f;
    float t   = big ? r : az;                   // t in [0, 1]
    float s   = t * t;
    float p   =                     -0.01172120f;
    p = __builtin_fmaf(p, s,         0.05265332f);
    p = __builtin_fmaf(p, s,        -0.11643287f);
    p = __builtin_fmaf(p, s,         0.19354346f);
    p = __builtin_fmaf(p, s,        -0.33262347f);
    p = __builtin_fmaf(p, s,         0.99997726f);
    float a = t * p;
    a = big ? (1.57079632679489662f - a) : a;
    return __builtin_copysignf(a, z);
}

// Async global->LDS. LDS dest = wave-uniform base + lane*size (HW semantics);
// global src is per-lane. Size must be a literal.
__device__ __forceinline__ void copy16_lds(const float* g, float* l) {
    __builtin_amdgcn_global_load_lds(
        (const __attribute__((address_space(1))) unsigned int*)g,
        (__attribute__((address_space(3))) unsigned int*)l, 16, 0, 0);
}
__device__ __forceinline__ void copy4_lds(const float* g, float* l) {
    __builtin_amdgcn_global_load_lds(
        (const __attribute__((address_space(1))) unsigned int*)g,
        (__attribute__((address_space(3))) unsigned int*)l, 4, 0, 0);
}

// Stage one tile's w+q into LDS: exactly 14 DMA instructions per wave,
// identical count on every wave and every tile (vmcnt stays exact).
// Wave stripe = 1600 floats = 6x(64 lanes x 16B) + 1x(64 lanes x 4B).
// Per-lane src clamp keeps the final tile's overhang in-bounds.
__device__ __forceinline__ void stage_tile(
        float* wl, float* ql,
        const float* __restrict__ w, const float* __restrict__ q,
        int tile, int wave_f, int lane)
{
    const int tb = tile * TILEF;
    #pragma unroll
    for (int r = 0; r < 6; ++r) {
        const int f  = wave_f + r * 256;            // wave-uniform float offset
        int sf = tb + f + lane * 4;                 // per-lane src float index
        sf = min(sf, WQF - 4);
        copy16_lds(w + sf, wl + f);
        copy16_lds(q + sf, ql + f);
    }
    const int f  = wave_f + 1536;
    int sf = tb + f + lane;
    sf = min(sf, WQF - 1);
    copy4_lds(w + sf, wl + f);
    copy4_lds(q + sf, ql + f);
}

// Per-thread x patch (5x5 window) -> registers. Lanes in 25-groups share a
// patch; x is 196 KB, L1/L2-resident. Compiler inserts its own dependency
// waits for these register loads (they are not part of the counted vmcnt).
__device__ __forceinline__ void load_x(
        float (&xv)[NUM], const float* __restrict__ x, int o)
{
    const int oc = min(o, NOUT - 1);                // clamp tail addressing
    int rem = oc / NUM;                             // (c*OUT + i)*OUT + j
    const int j = rem % OUT;  rem /= OUT;
    const int i = rem % OUT;
    const int c = rem / OUT;
    const float* xp = x + (c * IMG + i) * IMG + j;
    #pragma unroll
    for (int u = 0; u < 5; ++u) {
        float4 a;
        __builtin_memcpy(&a, xp + u * IMG, sizeof(float4));   // dword-aligned ok
        xv[5*u+0] = a.x; xv[5*u+1] = a.y; xv[5*u+2] = a.z; xv[5*u+3] = a.w;
        xv[5*u+4] = xp[u * IMG + 4];
    }
}

__device__ __forceinline__ float compute25(
        const float* wl, const float* ql, const float (&xv)[NUM])
{
    float prod0 = 1.0f, prod1 = 1.0f;
    #pragma unroll
    for (int k = 0; k < NUM; ++k) {
        const float z = 10.0f * __builtin_fmaf(xv[k], wl[k], -ql[k]);
        const float a = fast_atan(z);
        const float term = __builtin_fmaf(a, 0.31830988618379067f, 1.1f);
        if (k & 1) prod1 *= term; else prod0 *= term;
    }
    // prod in (~0.6^25, ~1.6^25): fp32-safe, single log.
    return __logf(prod0 * prod1);
}

__global__ __launch_bounds__(OPB) void dendrite_kernel(
    const float* __restrict__ x,
    const float* __restrict__ w,
    const float* __restrict__ q,
    float* __restrict__ out)
{
    __shared__ float w_lds[2][TILEF];     // 2 x 25.6 KB
    __shared__ float q_lds[2][TILEF];     // 2 x 25.6 KB   (total 100 KiB -> 1 block/CU)

    const int tid    = threadIdx.x;
    const int lane   = tid & 63;
    const int wave_f = (tid >> 6) * 1600;   // per-wave staging stripe (floats)

    // One pipeline step: compute tile t from (wl,ql,xc); prefetch tile t+PBLK
    // into (wln,qln,xn). vmcnt(14) = "wait for everything except the 14 DMA
    // just issued" -> tile t's DMA + x regs + old store are complete, tile
    // t+1's 51.2 KB stays in flight across the barrier.
    auto step = [&](const float* wl, const float* ql, float* wln, float* qln,
                    float (&xc)[NUM], float (&xn)[NUM], int t) {
        const int  tnext    = t + PBLK;
        const bool has_next = (tnext < NTILES);          // wave-uniform
        __builtin_amdgcn_s_barrier();                    // next buf free to overwrite
        if (has_next) {
            stage_tile(wln, qln, w, q, tnext, wave_f, lane);
            asm volatile("s_waitcnt vmcnt(14)" ::: "memory");
        } else {
            asm volatile("s_waitcnt vmcnt(0)" ::: "memory");
        }
        __builtin_amdgcn_s_barrier();                    // tile t visible block-wide
        const int o = t * OPB + tid;
        if (has_next) load_x(xn, x, o + PBLK * OPB);     // latency hides under compute
        if (o < NOUT)
            out[o] = compute25(&wl[tid * NUM], &ql[tid * NUM], xc);
    };

    // Prologue: stage first tile, load its x patch.
    int t = blockIdx.x;
    float xA[NUM], xB[NUM];
    stage_tile(w_lds[0], q_lds[0], w, q, t, wave_f, lane);
    load_x(xA, x, t * OPB + tid);

    // Steady loop: 2 steps per iteration for static register double-buffering.
    for (;;) {
        step(w_lds[0], q_lds[0], w_lds[1], q_lds[1], xA, xB, t);
        t += PBLK;
        if (t >= NTILES) break;
        step(w_lds[1], q_lds[1], w_lds[0], q_lds[0], xB, xA, t);
        t += PBLK;
        if (t >= NTILES) break;
    }
}

extern "C" void kernel_launch(void* const* d_in, const int* in_sizes, int n_in,
                              void* d_out, int out_size, void* d_ws, size_t ws_size,
                              hipStream_t stream) {
    const float* x = (const float*)d_in[0];
    const float* w = (const float*)d_in[1];
    const float* q = (const float*)d_in[2];
    float* out = (float*)d_out;

    dendrite_kernel<<<PBLK, OPB, 0, stream>>>(x, w, q, out);   // 256 persistent blocks
}

// Round 3
// 225.457 us; speedup vs baseline: 1.0936x; 1.0936x over previous
//
#include <hip/hip_runtime.h>

// Problem constants (from reference setup_inputs):
//   x: (1, 3, 128, 128) fp32
//   w: (3, 124, 124, 25, 5, 5) fp32
//   q: (3, 124, 124, 25, 5, 5) fp32
//   out: (1, 3, 124, 124, 25) fp32
// out[o] = log( prod_{k=0..24} (1.1 + atan(10*(x_k*w_k - q_k))/pi) )
//
// R6 design: R4 structure + NON-TEMPORAL staging of w/q.
// R3/R4/R5 post-mortem: three structures (register scatter @63% occ, DMA+drain
// @26%, persistent counted-vmcnt @10%) all pinned at ~2.6 TB/s combined read
// with every pipe idle -> the wall is downstream of the CUs. FETCH_SIZE is the
// discriminator: R3 pulled 150 MB from HBM (86.7us), R4/R5 only 113 MB
// (87.5/92.5us) -- the L3-HIT path (122 MB) back-solves to ~1.4 TB/s and is
// the critical path; the HBM path is underused (1.3-1.8 of 6.3 TB/s).
// w/q have ZERO reuse (each byte read once per dispatch); caching them in
// L2/L3 is pure harm. aux=2 on global_load_lds emits the `nt` (non-temporal/
// evict-first) cache policy: w/q lines stop persisting in L2/MALL, so in
// steady state the whole 230 MB streams from HBM on the fast path.
// x (196 KB, heavily reused) keeps normal caching.

#define IMG   128
#define OUT   124
#define NUM   25
#define NPATCH (3 * OUT * OUT)
#define NOUT  (NPATCH * NUM)               // 1,153,200 outputs
#define OPB   256                          // outputs (= threads) per block

// Minimax atan, |err| ~ 2e-6 over all inputs. Range-reduce with v_rcp_f32.
__device__ __forceinline__ float fast_atan(float z) {
    float az  = __builtin_fabsf(z);
    float r   = __builtin_amdgcn_rcpf(az);
    bool  big = az > 1.0f;
    float t   = big ? r : az;                   // t in [0, 1]
    float s   = t * t;
    float p   =                     -0.01172120f;
    p = __builtin_fmaf(p, s,         0.05265332f);
    p = __builtin_fmaf(p, s,        -0.11643287f);
    p = __builtin_fmaf(p, s,         0.19354346f);
    p = __builtin_fmaf(p, s,        -0.33262347f);
    p = __builtin_fmaf(p, s,         0.99997726f);
    float a = t * p;
    a = big ? (1.57079632679489662f - a) : a;
    return __builtin_copysignf(a, z);
}

// Async global->LDS, 16 B per lane, NON-TEMPORAL (aux=2 -> `nt` cpol bit:
// evict-first in L2/MALL, no persistence for the zero-reuse w/q streams).
// LDS dest is wave-uniform base + lane*16 (HW semantics); global src per-lane.
__device__ __forceinline__ void copy16_lds_nt(float* l, const float* g) {
    __builtin_amdgcn_global_load_lds(
        (const __attribute__((address_space(1))) unsigned int*)g,
        (__attribute__((address_space(3))) unsigned int*)l,
        16 /*bytes (literal)*/, 0 /*offset*/, 2 /*aux: NT*/);
}

__global__ __launch_bounds__(OPB) void dendrite_kernel(
    const float* __restrict__ x,
    const float* __restrict__ w,
    const float* __restrict__ q,
    float* __restrict__ out)
{
    __shared__ float w_lds[OPB * NUM];     // 6400 floats = 25.6 KB
    __shared__ float q_lds[OPB * NUM];     // 6400 floats = 25.6 KB

    const int tid = threadIdx.x;
    const int wvb = tid & ~63;             // wave-uniform lane base
    const long long o_base = (long long)blockIdx.x * OPB;
    const int nrem = min(OPB, (int)(NOUT - o_base));   // 256, last block 176
    const int lim4 = (nrem * NUM) >> 2;    // float4 chunks to stage (1600/1100)

    const float* wsrc = w + o_base * NUM;
    const float* qsrc = q + o_base * NUM;

    // ---- Stage w, q: 7+7 contiguous fire-and-forget NT rounds, no waits ----
    #pragma unroll
    for (int r = 0; r < 7; ++r) {
        const int idx4 = r * OPB + tid;
        if (idx4 < lim4)
            copy16_lds_nt(&w_lds[(r * OPB + wvb) * 4], wsrc + idx4 * 4);
    }
    #pragma unroll
    for (int r = 0; r < 7; ++r) {
        const int idx4 = r * OPB + tid;
        if (idx4 < lim4)
            copy16_lds_nt(&q_lds[(r * OPB + wvb) * 4], qsrc + idx4 * 4);
    }

    // ---- x patch -> registers, overlapped with the staging flight ----
    // x is 196 KB with heavy reuse: normal (cached) loads.
    const int o  = (int)o_base + tid;
    const int oc = min(o, NOUT - 1);       // clamp tail threads' addressing
    int rem = oc / NUM;                    // (c*OUT + i)*OUT + j
    const int j = rem % OUT;  rem /= OUT;
    const int i = rem % OUT;
    const int c = rem / OUT;
    const float* xp = x + ((long long)c * IMG + i) * IMG + j;

    float xv[NUM];
    #pragma unroll
    for (int u = 0; u < 5; ++u) {
        float4 a;
        __builtin_memcpy(&a, xp + u * IMG, sizeof(float4)); // dword-aligned ok
        xv[5*u+0] = a.x; xv[5*u+1] = a.y; xv[5*u+2] = a.z; xv[5*u+3] = a.w;
        xv[5*u+4] = xp[u * IMG + 4];
    }

    // Drain the global_load_lds queue once, then make LDS visible block-wide.
    asm volatile("s_waitcnt vmcnt(0)" ::: "memory");
    __syncthreads();

    // ---- Pure VALU epilogue: LDS reads at odd stride 25 (conflict-free) ----
    if (tid < nrem) {
        const float* wl = &w_lds[tid * NUM];
        const float* ql = &q_lds[tid * NUM];
        float prod0 = 1.0f, prod1 = 1.0f;
        #pragma unroll
        for (int k = 0; k < NUM; ++k) {
            const float z = 10.0f * __builtin_fmaf(xv[k], wl[k], -ql[k]);
            const float a = fast_atan(z);
            const float term = __builtin_fmaf(a, 0.31830988618379067f, 1.1f);
            if (k & 1) prod1 *= term; else prod0 *= term;
        }
        // prod in (~0.6^25, ~1.6^25): fp32-safe, single log.
        out[o] = __logf(prod0 * prod1);
    }
}

extern "C" void kernel_launch(void* const* d_in, const int* in_sizes, int n_in,
                              void* d_out, int out_size, void* d_ws, size_t ws_size,
                              hipStream_t stream) {
    const float* x = (const float*)d_in[0];
    const float* w = (const float*)d_in[1];
    const float* q = (const float*)d_in[2];
    float* out = (float*)d_out;

    const int grid = (NOUT + OPB - 1) / OPB;   // 4505 blocks
    dendrite_kernel<<<grid, OPB, 0, stream>>>(x, w, q, out);
}